// Round 9
// baseline (1392.953 us; speedup 1.0000x reference)
//
#include <hip/hip_runtime.h>

// NeuralBPDecoder: sparse BP over a 0.1%-dense parity matrix.
// Round 15: DIFFERENTIAL AMPLIFICATION measurement round. r14's split was
// supposed to give per-phase timing, but the harness's 2GB re-poison fills
// (~330us each) occupy the entire top-5 table and hid both kernels. Nine
// rounds of mechanism-level fixes (scan MLP, gather widths, XCD locality,
// barriers, idx residency) are all <50us movers while kernel-sum sits at
// ~400us (bench - 550us fixed overhead). This round: scan runs 2x (pass 0
// discarded, anti-DCE asm guard; pass 1 inserts) and the decode iteration
// loop runs 3x (bel re-init from regs per rep -> identical results; out
// written last rep; barrier ids offset per rep). Rows are labeled by kernel
// name: scan row = 2S, decode row = I+3L, bench delta = S+2L. Two equations
// + up to two direct rows => S and L pinned even if one row stays hidden.
// Kernels otherwise byte-identical to r14.

#define C_NUM 8192
#define V_NUM 16384
#define B_NUM 32
#define RW 64   // storage slots per check row (mean nnz 16.4)
#define CW 32   // storage slots per var col  (mean nnz  8.2)

#define RQ 12   // u64 idx batches per row in LDS: 48 idx (max row nnz ~33)
#define CQ 8    // u64 idx batches per col in LDS: 32 idx (max col nnz ~20)
#define RQ_S 13 // LDS row stride (u64) - breaks bank alignment
#define CQ_S 9  // LDS col stride (u64)

#define NBLK 256            // decode: 1 block/CU (LDS-forced)
#define NTHR 1024

#define NBLK_A 2048         // scan: 8 blocks/CU, 32 waves/CU
#define NTHR_A 256
#define NT_A (NBLK_A * NTHR_A)   // 524288 threads; 64 float4 each

#define WCAP 256            // LDS edge slots per wave (scan mean 16.4/wave)

#define BEL_SL (16400 * 4)  // floats per bel slice (dummy vi=16384 pad inside)
#define CMS_SL (8200 * 4)   // floats per cms slice (dummy ci=8192 pad inside)

#define NREP 3              // decode loop amplification factor
#define BARS_PER_REP 30     // 1 init + 29 iteration barriers

typedef unsigned short u16;
typedef unsigned int u32;
typedef unsigned long long u64;

#define NBAR 96
#define BAR_STRIDE 64              // u32s between counters (256 B)

__device__ __forceinline__ float agent_ldf(const float* p) {
    return __hip_atomic_load(p, __ATOMIC_RELAXED, __HIP_MEMORY_SCOPE_AGENT);
}
__device__ __forceinline__ void agent_stf(float* p, float v) {
    __hip_atomic_store(p, v, __ATOMIC_RELAXED, __HIP_MEMORY_SCOPE_AGENT);
}
__device__ __forceinline__ u64 agent_ld64(const u64* p) {
    return __hip_atomic_load(p, __ATOMIC_RELAXED, __HIP_MEMORY_SCOPE_AGENT);
}
__device__ __forceinline__ int agent_ldi(const int* p) {
    return __hip_atomic_load(p, __ATOMIC_RELAXED, __HIP_MEMORY_SCOPE_AGENT);
}
__device__ __forceinline__ void agent_st16(u16* p, u16 v) {
    __hip_atomic_store(p, v, __ATOMIC_RELAXED, __HIP_MEMORY_SCOPE_AGENT);
}

// Relaxed-only grid barrier (decode kernel only). Sound because:
// __syncthreads + explicit vmcnt drain commit all stores to their coherence
// point before thread 0 signals; cross-XCD data uses sc1 (IF); intra-XCD
// data only needs L2.
__device__ __forceinline__ void grid_barrier(u32* bars, int id) {
    __syncthreads();
    if (threadIdx.x == 0) {
        u32* base = bars + id * 8 * BAR_STRIDE;
        asm volatile("s_waitcnt vmcnt(0) lgkmcnt(0)" ::: "memory");
        __hip_atomic_fetch_add(base + (blockIdx.x & 7) * BAR_STRIDE, 1u,
                               __ATOMIC_RELAXED, __HIP_MEMORY_SCOPE_AGENT);
        u32 sum;
        do {
            sum = 0;
#pragma unroll
            for (int g = 0; g < 8; ++g)
                sum += __hip_atomic_load(base + g * BAR_STRIDE,
                                         __ATOMIC_RELAXED, __HIP_MEMORY_SCOPE_AGENT);
            if (sum < (u32)NBLK) __builtin_amdgcn_s_sleep(4);
        } while (sum < (u32)NBLK);
        asm volatile("" ::: "memory");
    }
    __syncthreads();
}

__device__ __forceinline__ float fast_tanh_half(float x) {
    float ax = fabsf(x);
    float e = __expf(-ax);
    return copysignf((1.0f - e) / (1.0f + e), x);
}

// 16-wide gather with ONE wait. LOCAL: sc0 (SE scope: bypass CU L1, served
// by the XCD's L2). FALLBACK: agent (sc1 -> IF). All 16 slots are always
// valid addresses (tail idx -> zeroed dummy pad -> contributes +0.0f).
template<bool LOCAL>
__device__ __forceinline__ float sum16(const float* __restrict__ base,
                                       const u64* __restrict__ q4, int b4) {
    const float* a[16];
#pragma unroll
    for (int p = 0; p < 4; ++p) {
        u64 q = q4[p];                       // ds_read_b64 (idx from LDS)
        a[4 * p + 0] = base + (int)(q & 0xFFFFu) * 4 + b4;
        a[4 * p + 1] = base + (int)((q >> 16) & 0xFFFFu) * 4 + b4;
        a[4 * p + 2] = base + (int)((q >> 32) & 0xFFFFu) * 4 + b4;
        a[4 * p + 3] = base + (int)(q >> 48) * 4 + b4;
    }
    float r[16];
    if (LOCAL) {
        asm volatile(
            "global_load_dword %0, %16, off sc0\n\t"
            "global_load_dword %1, %17, off sc0\n\t"
            "global_load_dword %2, %18, off sc0\n\t"
            "global_load_dword %3, %19, off sc0\n\t"
            "global_load_dword %4, %20, off sc0\n\t"
            "global_load_dword %5, %21, off sc0\n\t"
            "global_load_dword %6, %22, off sc0\n\t"
            "global_load_dword %7, %23, off sc0\n\t"
            "global_load_dword %8, %24, off sc0\n\t"
            "global_load_dword %9, %25, off sc0\n\t"
            "global_load_dword %10, %26, off sc0\n\t"
            "global_load_dword %11, %27, off sc0\n\t"
            "global_load_dword %12, %28, off sc0\n\t"
            "global_load_dword %13, %29, off sc0\n\t"
            "global_load_dword %14, %30, off sc0\n\t"
            "global_load_dword %15, %31, off sc0\n\t"
            "s_waitcnt vmcnt(0)"
            : "=&v"(r[0]), "=&v"(r[1]), "=&v"(r[2]), "=&v"(r[3]),
              "=&v"(r[4]), "=&v"(r[5]), "=&v"(r[6]), "=&v"(r[7]),
              "=&v"(r[8]), "=&v"(r[9]), "=&v"(r[10]), "=&v"(r[11]),
              "=&v"(r[12]), "=&v"(r[13]), "=&v"(r[14]), "=&v"(r[15])
            : "v"(a[0]), "v"(a[1]), "v"(a[2]), "v"(a[3]),
              "v"(a[4]), "v"(a[5]), "v"(a[6]), "v"(a[7]),
              "v"(a[8]), "v"(a[9]), "v"(a[10]), "v"(a[11]),
              "v"(a[12]), "v"(a[13]), "v"(a[14]), "v"(a[15])
            : "memory");
    } else {
#pragma unroll
        for (int j = 0; j < 16; ++j) r[j] = agent_ldf(a[j]);
    }
    float s0 = (r[0] + r[1]) + (r[2] + r[3]);
    float s1 = (r[4] + r[5]) + (r[6] + r[7]);
    float s2 = (r[8] + r[9]) + (r[10] + r[11]);
    float s3 = (r[12] + r[13]) + (r[14] + r[15]);
    return (s0 + s1) + (s2 + s3);
}

// ========== KERNEL A: scan + CSR build (2x amplified this round) ==========
__global__ __launch_bounds__(NTHR_A, 8)
void scan_build(const float* __restrict__ H,
                int* __restrict__ row_cnt, int* __restrict__ col_cnt,
                u16* __restrict__ row_idx, u16* __restrict__ col_idx) {
    __shared__ u32 lds_edges[(NTHR_A / 64) * WCAP];   // 4 KB
    const int lane = threadIdx.x & 63;
    u32* const wl = lds_edges + (threadIdx.x >> 6) * WCAP;
    const u64 ltmask = (1ull << lane) - 1ull;
    const float4* Hv = (const float4*)H;
    const u32 t0 = blockIdx.x * NTHR_A + threadIdx.x;
    int wave_cnt = 0;
#pragma unroll 1
    for (int pass = 0; pass < 2; ++pass) {   // AMPLIFICATION: pass 0 discarded
        int wb = 0;
#pragma unroll 1
        for (int i = 0; i < 8; ++i) {
            float4 h[8];                       // 8 independent loads in flight
#pragma unroll
            for (int k = 0; k < 8; ++k)
                h[k] = Hv[t0 + (u32)(i * 8 + k) * (u32)NT_A];
#pragma unroll
            for (int k = 0; k < 8; ++k) {
                u32 eb = (t0 + (u32)(i * 8 + k) * (u32)NT_A) * 4u;
                float vals[4] = {h[k].x, h[k].y, h[k].z, h[k].w};
#pragma unroll
                for (int kk = 0; kk < 4; ++kk) {
                    bool nz = vals[kk] != 0.0f;
                    u64 bb = __ballot(nz);
                    if (bb) {                  // ~6% of ballots
                        if (nz) {
                            int off = wb + (int)__popcll(bb & ltmask);
                            if (off < WCAP) wl[off] = eb + kk;
                        }
                        wb += (int)__popcll(bb);
                    }
                }
            }
        }
        // anti-DCE: wb live + memory clobber makes pass-0 work observable
        asm volatile("" : "+v"(wb) :: "memory");
        wave_cnt = wb < WCAP ? wb : WCAP;
    }
    // per-wave insertion ONCE (counters host-zeroed; no cross-block sync)
    for (int e = lane; e < wave_cnt; e += 64) {
        u32 ee = wl[e];
        int c = (int)(ee >> 14);              // V = 2^14
        int v = (int)(ee & (V_NUM - 1));
        int rs = atomicAdd(&row_cnt[c], 1);   // device scope -> IF
        if (rs < RW) agent_st16(&row_idx[(size_t)c * RW + rs], (u16)v);
        int cs = atomicAdd(&col_cnt[v], 1);
        if (cs < CW) agent_st16(&col_idx[(size_t)v * CW + cs], (u16)c);
    }
}

// ========== KERNEL B: decode (loop 3x amplified this round) ==========
template<bool LOCAL>
__device__ __forceinline__ void decode_tail(
    int G, int R,
    const float* __restrict__ synd, const float* __restrict__ llr,
    const int* __restrict__ row_cnt, const int* __restrict__ col_cnt,
    const u16* __restrict__ row_idx, const u16* __restrict__ col_idx,
    float* __restrict__ bel_x, float* __restrict__ cms_x,
    u32* __restrict__ bars, float* __restrict__ out,
    u64* ls_row, u64* ls_col,
    float wvc, float wcv, float d)
{
    const int t = threadIdx.x;
    const int b4 = t & 3;
    const int qid = t >> 2;                  // 0..255
    float* const belS = bel_x + (size_t)G * BEL_SL;
    float* const cmsS = cms_x + (size_t)G * CMS_SL;

    // ---- one-time: copy group's CSR indices into LDS (tails -> dummy) ----
    for (int e = t; e < 256 * RQ; e += NTHR) {
        int rl = e / RQ, p = e - rl * RQ;
        int c = (R << 8) + rl;
        int n = agent_ldi(&row_cnt[c]); n = n > 4 * RQ ? 4 * RQ : n;
        u64 q = agent_ld64(&((const u64*)(row_idx + (size_t)c * RW))[p]);
        int j = 4 * p;
        u64 a0 = (j + 0 < n) ? (q & 0xFFFFu) : (u64)V_NUM;
        u64 a1 = (j + 1 < n) ? ((q >> 16) & 0xFFFFu) : (u64)V_NUM;
        u64 a2 = (j + 2 < n) ? ((q >> 32) & 0xFFFFu) : (u64)V_NUM;
        u64 a3 = (j + 3 < n) ? (q >> 48) : (u64)V_NUM;
        ls_row[rl * RQ_S + p] = a0 | (a1 << 16) | (a2 << 32) | (a3 << 48);
    }
    for (int e = t; e < 512 * CQ; e += NTHR) {
        int gl = e >> 3, p = e & 7;
        int v = (gl < 256) ? ((R << 8) + gl) : (C_NUM + (R << 8) + (gl - 256));
        int n = agent_ldi(&col_cnt[v]); n = n > 4 * CQ ? 4 * CQ : n;
        u64 q = agent_ld64(&((const u64*)(col_idx + (size_t)v * CW))[p]);
        int j = 4 * p;
        u64 a0 = (j + 0 < n) ? (q & 0xFFFFu) : (u64)C_NUM;
        u64 a1 = (j + 1 < n) ? ((q >> 16) & 0xFFFFu) : (u64)C_NUM;
        u64 a2 = (j + 2 < n) ? ((q >> 32) & 0xFFFFu) : (u64)C_NUM;
        u64 a3 = (j + 3 < n) ? (q >> 48) : (u64)C_NUM;
        ls_col[gl * CQ_S + p] = a0 | (a1 << 16) | (a2 << 32) | (a3 << 48);
    }
    // ---- one-time per-thread state ----
    const int c_my = (R << 8) + qid;
    const int v0_my = (R << 8) + qid;
    const int v1_my = C_NUM + (R << 8) + qid;
    int nrow;  { int n = agent_ldi(&row_cnt[c_my]);  nrow  = n > 4*RQ ? 4*RQ : n; }
    int ncol0; { int n = agent_ldi(&col_cnt[v0_my]); ncol0 = n > 4*CQ ? 4*CQ : n; }
    int ncol1; { int n = agent_ldi(&col_cnt[v1_my]); ncol1 = n > 4*CQ ? 4*CQ : n; }
    const int b = (G << 2) + b4;
    const float ss = 1.0f - 2.0f * synd[b * C_NUM + c_my];
    const float llr0 = llr[b * V_NUM + v0_my];
    const float llr1 = llr[b * V_NUM + v1_my];
    const u64* const rowL  = ls_row + qid * RQ_S;
    const u64* const colL0 = ls_col + qid * CQ_S;
    const u64* const colL1 = ls_col + (256 + qid) * CQ_S;
    float* const cms_own  = cmsS + c_my * 4 + b4;
    float* const bel_own0 = belS + v0_my * 4 + b4;
    float* const bel_own1 = belS + v1_my * 4 + b4;

#pragma unroll 1
    for (int rep = 0; rep < NREP; ++rep) {   // AMPLIFICATION: identical reps
        float bel0 = llr0, bel1 = llr1;
        if (LOCAL) { *bel_own0 = bel0; *bel_own1 = bel1; }
        else { agent_stf(bel_own0, bel0); agent_stf(bel_own1, bel1); }

        grid_barrier(bars, 1 + rep * BARS_PER_REP);  // bel init visible
        int barid = 2 + rep * BARS_PER_REP;

        for (int it = 0; it < 15; ++it) {
            // ---- v->c ----
            {
                float sum = sum16<LOCAL>(belS, rowL, b4);
                if (__any(nrow > 16)) sum += sum16<LOCAL>(belS, rowL + 4, b4);
                if (__any(nrow > 32)) sum += sum16<LOCAL>(belS, rowL + 8, b4);
                float m = ss * fast_tanh_half(wvc * sum);
                if (LOCAL) *cms_own = m; else agent_stf(cms_own, m);
            }
            grid_barrier(bars, barid++);

            // ---- c->v ----
            bool last = (it == 14);
            float sum0 = sum16<LOCAL>(cmsS, colL0, b4);
            if (__any(ncol0 > 16)) sum0 += sum16<LOCAL>(cmsS, colL0 + 4, b4);
            float sum1 = sum16<LOCAL>(cmsS, colL1, b4);
            if (__any(ncol1 > 16)) sum1 += sum16<LOCAL>(cmsS, colL1 + 4, b4);

            float nb0 = d * bel0 + (1.0f - d) * (llr0 + wcv * sum0);
            float nb1 = d * bel1 + (1.0f - d) * (llr1 + wcv * sum1);
            bel0 = nb0; bel1 = nb1;
            if (!last) {
                if (LOCAL) { *bel_own0 = nb0; *bel_own1 = nb1; }
                else { agent_stf(bel_own0, nb0); agent_stf(bel_own1, nb1); }
                grid_barrier(bars, barid++);
            } else if (rep == NREP - 1) {
                out[b * V_NUM + v0_my] = 1.0f / (1.0f + __expf(nb0));
                out[b * V_NUM + v1_my] = 1.0f / (1.0f + __expf(nb1));
            }
            // rep < NREP-1, it==14: no store needed; next rep re-inits bel.
        }
    }
}

__global__ __launch_bounds__(NTHR, 1) __attribute__((amdgpu_waves_per_eu(4, 4)))
void bp_decode(const float* __restrict__ synd,   // (B, C)
               const float* __restrict__ llr,    // (B, V)
               const float* __restrict__ w_vc_p,
               const float* __restrict__ w_cv_p,
               const float* __restrict__ damp_p,
               const int* __restrict__ row_cnt, const int* __restrict__ col_cnt,
               const u16* __restrict__ row_idx, const u16* __restrict__ col_idx,
               float* __restrict__ bel_x, float* __restrict__ cms_x,
               u32* __restrict__ bars, int* __restrict__ xcd_cnt,
               float* __restrict__ out) {        // (B, V)
    const int t = threadIdx.x;
    const int tid = blockIdx.x * NTHR + t;

    // 84 KB LDS pool: forces 1 block/CU -> 256 blocks 1-per-CU -> 32/XCD
    // (checked at runtime anyway).
    __shared__ u64 shpool[10496];
    __shared__ int s_xcd, s_rank;
    u64* const ls_row = shpool;                   // 256*RQ_S
    u64* const ls_col = shpool + 256 * RQ_S;      // 512*CQ_S

    // ---- XCD self-registration (counters host-zeroed) ----
    if (t == 0) {
        u32 x;
        asm volatile("s_getreg_b32 %0, hwreg(HW_REG_XCC_ID)" : "=s"(x));
        x &= 15;
        s_xcd = (int)x;
        s_rank = atomicAdd(&xcd_cnt[x], 1);   // device scope -> IF
    }
    // ---- dummy gather pads (zeroed once) ----
    if (tid < 32) {            // bel pads: slice g, dummy vi=16384
        int g = tid >> 2, j = tid & 3;
        agent_stf(&bel_x[(size_t)g * BEL_SL + V_NUM * 4 + j], 0.0f);
    } else if (tid < 64) {     // cms pads: slice g, dummy ci=8192
        int g = (tid - 32) >> 2, j = tid & 3;
        agent_stf(&cms_x[(size_t)g * CMS_SL + C_NUM * 4 + j], 0.0f);
    }
    grid_barrier(bars, 0);     // registrations + pads complete

    bool balanced = true;
#pragma unroll
    for (int g = 0; g < 8; ++g) balanced &= (agent_ldi(&xcd_cnt[g]) == 32);

    const float wvc = w_vc_p[0];
    const float wcv = w_cv_p[0];
    const float d   = damp_p[0];

    if (balanced) {
        decode_tail<true>(s_xcd, s_rank, synd, llr, row_cnt, col_cnt,
                          row_idx, col_idx, bel_x, cms_x, bars, out,
                          ls_row, ls_col, wvc, wcv, d);
    } else {
        decode_tail<false>((int)(blockIdx.x >> 5), (int)(blockIdx.x & 31),
                           synd, llr, row_cnt, col_cnt,
                           row_idx, col_idx, bel_x, cms_x, bars, out,
                           ls_row, ls_col, wvc, wcv, d);
    }
}

extern "C" void kernel_launch(void* const* d_in, const int* in_sizes, int n_in,
                              void* d_out, int out_size, void* d_ws, size_t ws_size,
                              hipStream_t stream) {
    const float* synd = (const float*)d_in[0];   // (B, C)
    const float* H    = (const float*)d_in[1];   // (C, V)
    const float* llr  = (const float*)d_in[2];   // (B, V)
    const float* w_vc = (const float*)d_in[3];
    const float* w_cv = (const float*)d_in[4];
    const float* damp = (const float*)d_in[5];
    float* out = (float*)d_out;

    char* ws = (char*)d_ws;
    size_t off = 0;
    int* row_cnt = (int*)(ws + off); off += (size_t)C_NUM * 4;        // 32 KB
    int* col_cnt = (int*)(ws + off); off += (size_t)V_NUM * 4;        // 64 KB
    u16* row_idx = (u16*)(ws + off); off += (size_t)C_NUM * RW * 2;   // 1 MB
    u16* col_idx = (u16*)(ws + off); off += (size_t)V_NUM * CW * 2;   // 1 MB
    float* bel_x = (float*)(ws + off); off += (size_t)8 * BEL_SL * 4; // 2.1 MB
    float* cms_x = (float*)(ws + off); off += (size_t)8 * CMS_SL * 4; // 1.05 MB
    u32* bars  = (u32*)(ws + off); off += (size_t)NBAR * 8 * BAR_STRIDE * 4; // 192 KB
    int* xcd_cnt = (int*)(ws + off); off += 64;                       // 16 ints

    // zero CSR counters (96 KB) + barrier counters + xcd counters
    hipMemsetAsync(row_cnt, 0, (size_t)(C_NUM + V_NUM) * 4, stream);
    hipMemsetAsync(bars, 0, (size_t)NBAR * 8 * BAR_STRIDE * 4 + 64, stream);

    // Kernel A: scan + CSR build (plain launch, high occupancy)
    hipLaunchKernelGGL(scan_build, dim3(NBLK_A), dim3(NTHR_A), 0, stream,
                       H, row_cnt, col_cnt, row_idx, col_idx);

    // Kernel B: decode (cooperative, 1 block/CU, XCD-local)
    void* args[] = {
        (void*)&synd, (void*)&llr, (void*)&w_vc, (void*)&w_cv, (void*)&damp,
        (void*)&row_cnt, (void*)&col_cnt, (void*)&row_idx, (void*)&col_idx,
        (void*)&bel_x, (void*)&cms_x, (void*)&bars, (void*)&xcd_cnt,
        (void*)&out
    };
    hipLaunchCooperativeKernel((const void*)bp_decode,
                               dim3(NBLK), dim3(NTHR), args, 0, stream);
}

// Round 11
// 890.147 us; speedup vs baseline: 1.5649x; 1.5649x over previous
//
#include <hip/hip_runtime.h>

// NeuralBPDecoder: sparse BP over a 0.1%-dense parity matrix.
// Round 17: STRICT BISECT after r16's failure (two unproven mechanisms at
// once - L2-slot asm barrier + depth-8 scan - zero attribution). This round
// is r12's proven body (depth-2 rotate scan, CSR build, XCD-local sc0
// gathers) + r14's proven sum16 decode + exactly ONE new piece: per-XCD
// barriers implemented with the SAME relaxed IF-atomic counter mechanism as
// the proven grid barrier, but counting to 32 on a private (xcd,id) counter.
// r15 measured the loop at 166us with ~116us in 29 global barriers (~4us
// each: arrival + IF poll + 256-block skew). Per-XCD barriers wait only on
// the XCD's own 32 blocks: skew tail shrinks, XCDs decouple, detect is one
// counter read. No new visibility assumptions (arrival/poll via IF as
// always; intra-XCD data via r12-proven plain-store -> sc0-load, ordered by
// the same vmcnt drain). Fallback (unbalanced placement): global barriers.

#define C_NUM 8192
#define V_NUM 16384
#define B_NUM 32
#define RW 64   // storage slots per check row (mean nnz 16.4)
#define CW 32   // storage slots per var col  (mean nnz  8.2)

#define RQ 12   // u64 idx batches per row in LDS: 48 idx (max row nnz ~33)
#define CQ 8    // u64 idx batches per col in LDS: 32 idx (max col nnz ~20)
#define RQ_S 13 // LDS row stride (u64) - breaks bank alignment
#define CQ_S 9  // LDS col stride (u64)

#define NBLK 256
#define NTHR 1024
#define NTH (NBLK * NTHR)   // 262144 threads, 16 waves/CU

#define WCAP 256            // LDS edge slots per wave (mean 32.8, >30 sigma safe)

#define BEL_SL (16400 * 4)  // floats per bel slice (dummy vi=16384 pad inside)
#define CMS_SL (8200 * 4)   // floats per cms slice (dummy ci=8192 pad inside)

typedef unsigned short u16;
typedef unsigned int u32;
typedef unsigned long long u64;

#define NBAR 32             // global barrier ids (0,1 balanced; all on fallback)
#define BAR_STRIDE 64       // u32s between global counters (256 B)
#define NIDS 32             // per-XCD barrier ids (use 30)
#define XB_STRIDE 16        // u32s between per-XCD counters (64 B line each)

__device__ __forceinline__ float agent_ldf(const float* p) {
    return __hip_atomic_load(p, __ATOMIC_RELAXED, __HIP_MEMORY_SCOPE_AGENT);
}
__device__ __forceinline__ void agent_stf(float* p, float v) {
    __hip_atomic_store(p, v, __ATOMIC_RELAXED, __HIP_MEMORY_SCOPE_AGENT);
}
__device__ __forceinline__ u64 agent_ld64(const u64* p) {
    return __hip_atomic_load(p, __ATOMIC_RELAXED, __HIP_MEMORY_SCOPE_AGENT);
}
__device__ __forceinline__ int agent_ldi(const int* p) {
    return __hip_atomic_load(p, __ATOMIC_RELAXED, __HIP_MEMORY_SCOPE_AGENT);
}
__device__ __forceinline__ void agent_st16(u16* p, u16 v) {
    __hip_atomic_store(p, v, __ATOMIC_RELAXED, __HIP_MEMORY_SCOPE_AGENT);
}

// Global (grid) barrier: relaxed-only, IF-coherent counters (proven r6-r15).
__device__ __forceinline__ void grid_barrier(u32* bars, int id) {
    __syncthreads();
    if (threadIdx.x == 0) {
        u32* base = bars + id * 8 * BAR_STRIDE;
        asm volatile("s_waitcnt vmcnt(0) lgkmcnt(0)" ::: "memory");
        __hip_atomic_fetch_add(base + (blockIdx.x & 7) * BAR_STRIDE, 1u,
                               __ATOMIC_RELAXED, __HIP_MEMORY_SCOPE_AGENT);
        u32 sum;
        do {
            sum = 0;
#pragma unroll
            for (int g = 0; g < 8; ++g)
                sum += __hip_atomic_load(base + g * BAR_STRIDE,
                                         __ATOMIC_RELAXED, __HIP_MEMORY_SCOPE_AGENT);
            if (sum < (u32)NBLK) __builtin_amdgcn_s_sleep(4);
        } while (sum < (u32)NBLK);
        asm volatile("" ::: "memory");
    }
    __syncthreads();
}

// Per-XCD barrier: IDENTICAL mechanism (relaxed IF atomics + vmcnt drain),
// counting to 32 on this XCD's private (id-strided) counter. The vmcnt
// drain before arrival commits each block's plain stores to the XCD L2;
// counter==32 therefore implies all 32 blocks' stores are L2-visible for
// the sc0 gathers. One counter per crossing (host-zeroed, never reused).
__device__ __forceinline__ void xcd_barrier(u32* cnt) {
    __syncthreads();
    if (threadIdx.x == 0) {
        asm volatile("s_waitcnt vmcnt(0) lgkmcnt(0)" ::: "memory");
        __hip_atomic_fetch_add(cnt, 1u, __ATOMIC_RELAXED,
                               __HIP_MEMORY_SCOPE_AGENT);
        while (__hip_atomic_load(cnt, __ATOMIC_RELAXED,
                                 __HIP_MEMORY_SCOPE_AGENT) < 32u)
            __builtin_amdgcn_s_sleep(2);
        asm volatile("" ::: "memory");
    }
    __syncthreads();
}

__device__ __forceinline__ float fast_tanh_half(float x) {
    float ax = fabsf(x);
    float e = __expf(-ax);
    return copysignf((1.0f - e) / (1.0f + e), x);
}

// 16-wide gather with ONE wait (proven r14/r15). LOCAL: sc0 (bypass CU L1,
// served by XCD L2). FALLBACK: agent (sc1 -> IF). Tail idx -> zeroed pad.
template<bool LOCAL>
__device__ __forceinline__ float sum16(const float* __restrict__ base,
                                       const u64* __restrict__ q4, int b4) {
    const float* a[16];
#pragma unroll
    for (int p = 0; p < 4; ++p) {
        u64 q = q4[p];                       // ds_read_b64 (idx from LDS)
        a[4 * p + 0] = base + (int)(q & 0xFFFFu) * 4 + b4;
        a[4 * p + 1] = base + (int)((q >> 16) & 0xFFFFu) * 4 + b4;
        a[4 * p + 2] = base + (int)((q >> 32) & 0xFFFFu) * 4 + b4;
        a[4 * p + 3] = base + (int)(q >> 48) * 4 + b4;
    }
    float r[16];
    if (LOCAL) {
        asm volatile(
            "global_load_dword %0, %16, off sc0\n\t"
            "global_load_dword %1, %17, off sc0\n\t"
            "global_load_dword %2, %18, off sc0\n\t"
            "global_load_dword %3, %19, off sc0\n\t"
            "global_load_dword %4, %20, off sc0\n\t"
            "global_load_dword %5, %21, off sc0\n\t"
            "global_load_dword %6, %22, off sc0\n\t"
            "global_load_dword %7, %23, off sc0\n\t"
            "global_load_dword %8, %24, off sc0\n\t"
            "global_load_dword %9, %25, off sc0\n\t"
            "global_load_dword %10, %26, off sc0\n\t"
            "global_load_dword %11, %27, off sc0\n\t"
            "global_load_dword %12, %28, off sc0\n\t"
            "global_load_dword %13, %29, off sc0\n\t"
            "global_load_dword %14, %30, off sc0\n\t"
            "global_load_dword %15, %31, off sc0\n\t"
            "s_waitcnt vmcnt(0)"
            : "=&v"(r[0]), "=&v"(r[1]), "=&v"(r[2]), "=&v"(r[3]),
              "=&v"(r[4]), "=&v"(r[5]), "=&v"(r[6]), "=&v"(r[7]),
              "=&v"(r[8]), "=&v"(r[9]), "=&v"(r[10]), "=&v"(r[11]),
              "=&v"(r[12]), "=&v"(r[13]), "=&v"(r[14]), "=&v"(r[15])
            : "v"(a[0]), "v"(a[1]), "v"(a[2]), "v"(a[3]),
              "v"(a[4]), "v"(a[5]), "v"(a[6]), "v"(a[7]),
              "v"(a[8]), "v"(a[9]), "v"(a[10]), "v"(a[11]),
              "v"(a[12]), "v"(a[13]), "v"(a[14]), "v"(a[15])
            : "memory");
    } else {
#pragma unroll
        for (int j = 0; j < 16; ++j) r[j] = agent_ldf(a[j]);
    }
    float s0 = (r[0] + r[1]) + (r[2] + r[3]);
    float s1 = (r[4] + r[5]) + (r[6] + r[7]);
    float s2 = (r[8] + r[9]) + (r[10] + r[11]);
    float s3 = (r[12] + r[13]) + (r[14] + r[15]);
    return (s0 + s1) + (s2 + s3);
}

template<bool LOCAL>
__device__ __forceinline__ void decode_tail(
    int G, int R,
    const float* __restrict__ synd, const float* __restrict__ llr,
    const int* __restrict__ row_cnt, const int* __restrict__ col_cnt,
    const u16* __restrict__ row_idx, const u16* __restrict__ col_idx,
    float* __restrict__ bel_x, float* __restrict__ cms_x,
    u32* __restrict__ bars, u32* __restrict__ xb,   // xb: this XCD's counters
    float* __restrict__ out,
    u64* ls_row, u64* ls_col,
    float wvc, float wcv, float d)
{
    const int t = threadIdx.x;
    const int b4 = t & 3;
    const int qid = t >> 2;                  // 0..255
    float* const belS = bel_x + (size_t)G * BEL_SL;
    float* const cmsS = cms_x + (size_t)G * CMS_SL;

    // ---- copy this group's CSR indices into LDS (tails -> dummy idx) ----
    for (int e = t; e < 256 * RQ; e += NTHR) {
        int rl = e / RQ, p = e - rl * RQ;
        int c = (R << 8) + rl;
        int n = agent_ldi(&row_cnt[c]); n = n > 4 * RQ ? 4 * RQ : n;
        u64 q = agent_ld64(&((const u64*)(row_idx + (size_t)c * RW))[p]);
        int j = 4 * p;
        u64 a0 = (j + 0 < n) ? (q & 0xFFFFu) : (u64)V_NUM;
        u64 a1 = (j + 1 < n) ? ((q >> 16) & 0xFFFFu) : (u64)V_NUM;
        u64 a2 = (j + 2 < n) ? ((q >> 32) & 0xFFFFu) : (u64)V_NUM;
        u64 a3 = (j + 3 < n) ? (q >> 48) : (u64)V_NUM;
        ls_row[rl * RQ_S + p] = a0 | (a1 << 16) | (a2 << 32) | (a3 << 48);
    }
    for (int e = t; e < 512 * CQ; e += NTHR) {
        int gl = e >> 3, p = e & 7;
        int v = (gl < 256) ? ((R << 8) + gl) : (C_NUM + (R << 8) + (gl - 256));
        int n = agent_ldi(&col_cnt[v]); n = n > 4 * CQ ? 4 * CQ : n;
        u64 q = agent_ld64(&((const u64*)(col_idx + (size_t)v * CW))[p]);
        int j = 4 * p;
        u64 a0 = (j + 0 < n) ? (q & 0xFFFFu) : (u64)C_NUM;
        u64 a1 = (j + 1 < n) ? ((q >> 16) & 0xFFFFu) : (u64)C_NUM;
        u64 a2 = (j + 2 < n) ? ((q >> 32) & 0xFFFFu) : (u64)C_NUM;
        u64 a3 = (j + 3 < n) ? (q >> 48) : (u64)C_NUM;
        ls_col[gl * CQ_S + p] = a0 | (a1 << 16) | (a2 << 32) | (a3 << 48);
    }
    // ---- per-thread state ----
    const int c_my = (R << 8) + qid;
    const int v0_my = (R << 8) + qid;
    const int v1_my = C_NUM + (R << 8) + qid;
    int nrow;  { int n = agent_ldi(&row_cnt[c_my]);  nrow  = n > 4*RQ ? 4*RQ : n; }
    int ncol0; { int n = agent_ldi(&col_cnt[v0_my]); ncol0 = n > 4*CQ ? 4*CQ : n; }
    int ncol1; { int n = agent_ldi(&col_cnt[v1_my]); ncol1 = n > 4*CQ ? 4*CQ : n; }
    const int b = (G << 2) + b4;
    const float ss = 1.0f - 2.0f * synd[b * C_NUM + c_my];
    const float llr0 = llr[b * V_NUM + v0_my];
    const float llr1 = llr[b * V_NUM + v1_my];
    float bel0 = llr0, bel1 = llr1;
    if (LOCAL) {
        belS[v0_my * 4 + b4] = bel0;
        belS[v1_my * 4 + b4] = bel1;
    } else {
        agent_stf(&belS[v0_my * 4 + b4], bel0);
        agent_stf(&belS[v1_my * 4 + b4], bel1);
    }

    // init barrier: bel init + LDS idx visible group-wide
    if (LOCAL) xcd_barrier(xb); else grid_barrier(bars, 2);

    const u64* const rowL  = ls_row + qid * RQ_S;
    const u64* const colL0 = ls_col + qid * CQ_S;
    const u64* const colL1 = ls_col + (256 + qid) * CQ_S;
    float* const cms_own  = cmsS + c_my * 4 + b4;
    float* const bel_own0 = belS + v0_my * 4 + b4;
    float* const bel_own1 = belS + v1_my * 4 + b4;

    int barid = 1;   // xcd ids 1..29; fallback global ids 3..31
    for (int it = 0; it < 15; ++it) {
        // ---- v->c ----
        {
            float sum = sum16<LOCAL>(belS, rowL, b4);
            if (__any(nrow > 16)) sum += sum16<LOCAL>(belS, rowL + 4, b4);
            if (__any(nrow > 32)) sum += sum16<LOCAL>(belS, rowL + 8, b4);
            float m = ss * fast_tanh_half(wvc * sum);
            if (LOCAL) *cms_own = m; else agent_stf(cms_own, m);
        }
        if (LOCAL) xcd_barrier(xb + barid * XB_STRIDE);
        else grid_barrier(bars, 2 + barid);
        ++barid;

        // ---- c->v ----
        bool last = (it == 14);
        float sum0 = sum16<LOCAL>(cmsS, colL0, b4);
        if (__any(ncol0 > 16)) sum0 += sum16<LOCAL>(cmsS, colL0 + 4, b4);
        float sum1 = sum16<LOCAL>(cmsS, colL1, b4);
        if (__any(ncol1 > 16)) sum1 += sum16<LOCAL>(cmsS, colL1 + 4, b4);

        float nb0 = d * bel0 + (1.0f - d) * (llr0 + wcv * sum0);
        float nb1 = d * bel1 + (1.0f - d) * (llr1 + wcv * sum1);
        bel0 = nb0; bel1 = nb1;
        if (!last) {
            if (LOCAL) { *bel_own0 = nb0; *bel_own1 = nb1; }
            else { agent_stf(bel_own0, nb0); agent_stf(bel_own1, nb1); }
            if (LOCAL) xcd_barrier(xb + barid * XB_STRIDE);
            else grid_barrier(bars, 2 + barid);
            ++barid;
        } else {
            out[b * V_NUM + v0_my] = 1.0f / (1.0f + __expf(nb0));
            out[b * V_NUM + v1_my] = 1.0f / (1.0f + __expf(nb1));
        }
    }
}

__global__ __launch_bounds__(NTHR, 1)
void bp_fused(const float* __restrict__ H,      // (C, V)
              const float* __restrict__ synd,   // (B, C)
              const float* __restrict__ llr,    // (B, V)
              const float* __restrict__ w_vc_p,
              const float* __restrict__ w_cv_p,
              const float* __restrict__ damp_p,
              int* __restrict__ row_cnt, int* __restrict__ col_cnt,
              u16* __restrict__ row_idx, u16* __restrict__ col_idx,
              float* __restrict__ bel_x, float* __restrict__ cms_x,
              u32* __restrict__ bars, u32* __restrict__ xbars,
              int* __restrict__ xcd_cnt,
              float* __restrict__ out) {        // (B, V)
    const int t = threadIdx.x;
    const int tid = blockIdx.x * NTHR + t;
    const int lane = t & 63;

    // 84 KB static LDS: forces 1 block/CU -> 256 blocks 1-per-CU -> 32/XCD
    // (checked at runtime anyway).
    __shared__ u32 lds_edges[(NTHR / 64) * WCAP + 1024];  // 20 KB (incl pad)
    __shared__ u64 ls_row[256 * RQ_S];                    // 26 KB
    __shared__ u64 ls_col[512 * CQ_S];                    // 36 KB
    __shared__ int s_xcd, s_rank;
    u32* const wl = lds_edges + (t >> 6) * WCAP;

    // ---- XCD self-registration (counters host-zeroed) ----
    if (t == 0) {
        u32 x;
        asm volatile("s_getreg_b32 %0, hwreg(HW_REG_XCC_ID)" : "=s"(x));
        x &= 15;
        s_xcd = (int)x;
        s_rank = atomicAdd(&xcd_cnt[x], 1);   // device scope -> IF
    }
    // ---- dummy gather pads (zeroed once; scan below flushes all L2s of
    // any stale poison lines before these are ever read) ----
    if (tid < 32) {            // bel pads: slice g, dummy vi=16384
        int g = tid >> 2, j = tid & 3;
        agent_stf(&bel_x[(size_t)g * BEL_SL + V_NUM * 4 + j], 0.0f);
    } else if (tid < 64) {     // cms pads: slice g, dummy ci=8192
        int g = (tid - 32) >> 2, j = tid & 3;
        agent_stf(&cms_x[(size_t)g * CMS_SL + C_NUM * 4 + j], 0.0f);
    }

    // ---- P1a: stream dense H, compact nonzeros into per-wave LDS list ----
    // (r12's proven depth-2 hand pipeline, verbatim.)
    int wave_cnt;
    {
        const float4* Hv = (const float4*)H;
        const u64 ltmask = (1ull << lane) - 1ull;
        int wb = 0;
        int ta = tid;
        int tb = tid + 2 * NTH;
        float4 a0 = Hv[ta], a1 = Hv[ta + NTH];
        float4 b0 = Hv[tb], b1 = Hv[tb + NTH];
#pragma unroll 1
        for (int itn = 0; itn < 64; ++itn) {
            int tc = tb + 2 * NTH;
            float4 p0, p1;
            if (itn < 62) { p0 = Hv[tc]; p1 = Hv[tc + NTH]; }
            float vals[8] = {a0.x, a0.y, a0.z, a0.w, a1.x, a1.y, a1.z, a1.w};
#pragma unroll
            for (int k = 0; k < 8; ++k) {
                bool nz = vals[k] != 0.0f;
                u64 bb = __ballot(nz);
                if (bb) {
                    if (nz) {
                        int ee = (k < 4) ? (ta * 4 + k)
                                         : ((ta + NTH) * 4 + (k - 4));
                        int off = wb + (int)__popcll(bb & ltmask);
                        if (off < WCAP) wl[off] = (u32)ee;
                    }
                    wb += (int)__popcll(bb);
                }
            }
            a0 = b0; a1 = b1; b0 = p0; b1 = p1; ta = tb; tb = tc;
        }
        wave_cnt = wb < WCAP ? wb : WCAP;
    }
    // Barrier: counters/pads zeroed everywhere; registrations complete.
    grid_barrier(bars, 0);

    // ---- P1b: CSR insertion from LDS edge lists (~33 edges/wave) ----
    {
        for (int e = lane; e < wave_cnt; e += 64) {
            u32 ee = wl[e];
            int c = (int)(ee >> 14);             // V = 2^14
            int v = (int)(ee & (V_NUM - 1));
            int rs = atomicAdd(&row_cnt[c], 1);  // device-scope -> IF
            if (rs < RW) agent_st16(&row_idx[(size_t)c * RW + rs], (u16)v);
            int cs = atomicAdd(&col_cnt[v], 1);
            if (cs < CW) agent_st16(&col_idx[(size_t)v * CW + cs], (u16)c);
        }
    }
    grid_barrier(bars, 1);

    // ---- group assignment: physical XCD if balanced, else virtual ----
    int my_xcd = s_xcd, my_rank = s_rank;   // visible post-barrier
    bool balanced = true;
#pragma unroll
    for (int g = 0; g < 8; ++g) balanced &= (agent_ldi(&xcd_cnt[g]) == 32);

    const float wvc = w_vc_p[0];
    const float wcv = w_cv_p[0];
    const float d   = damp_p[0];

    if (balanced) {
        u32* xb = xbars + (size_t)my_xcd * NIDS * XB_STRIDE;
        decode_tail<true>(my_xcd, my_rank, synd, llr, row_cnt, col_cnt,
                          row_idx, col_idx, bel_x, cms_x, bars, xb, out,
                          ls_row, ls_col, wvc, wcv, d);
    } else {
        decode_tail<false>((int)(blockIdx.x >> 5), (int)(blockIdx.x & 31),
                           synd, llr, row_cnt, col_cnt,
                           row_idx, col_idx, bel_x, cms_x, bars, nullptr, out,
                           ls_row, ls_col, wvc, wcv, d);
    }
}

extern "C" void kernel_launch(void* const* d_in, const int* in_sizes, int n_in,
                              void* d_out, int out_size, void* d_ws, size_t ws_size,
                              hipStream_t stream) {
    const float* synd = (const float*)d_in[0];   // (B, C)
    const float* H    = (const float*)d_in[1];   // (C, V)
    const float* llr  = (const float*)d_in[2];   // (B, V)
    const float* w_vc = (const float*)d_in[3];
    const float* w_cv = (const float*)d_in[4];
    const float* damp = (const float*)d_in[5];
    float* out = (float*)d_out;

    char* ws = (char*)d_ws;
    size_t off = 0;
    int* row_cnt = (int*)(ws + off); off += (size_t)C_NUM * 4;        // 32 KB
    int* col_cnt = (int*)(ws + off); off += (size_t)V_NUM * 4;        // 64 KB
    u16* row_idx = (u16*)(ws + off); off += (size_t)C_NUM * RW * 2;   // 1 MB
    u16* col_idx = (u16*)(ws + off); off += (size_t)V_NUM * CW * 2;   // 1 MB
    float* bel_x = (float*)(ws + off); off += (size_t)8 * BEL_SL * 4; // 2.1 MB
    float* cms_x = (float*)(ws + off); off += (size_t)8 * CMS_SL * 4; // 1.05 MB
    // bars + xbars + xcd_cnt contiguous: ONE memset covers all three
    u32* bars  = (u32*)(ws + off); off += (size_t)NBAR * 8 * BAR_STRIDE * 4; // 64 KB
    u32* xbars = (u32*)(ws + off); off += (size_t)8 * NIDS * XB_STRIDE * 4;  // 16 KB
    int* xcd_cnt = (int*)(ws + off); off += 64;                              // 16 ints

    hipMemsetAsync(row_cnt, 0, (size_t)(C_NUM + V_NUM) * 4, stream);
    hipMemsetAsync(bars, 0,
                   (size_t)NBAR * 8 * BAR_STRIDE * 4
                 + (size_t)8 * NIDS * XB_STRIDE * 4 + 64, stream);

    void* args[] = {
        (void*)&H, (void*)&synd, (void*)&llr,
        (void*)&w_vc, (void*)&w_cv, (void*)&damp,
        (void*)&row_cnt, (void*)&col_cnt, (void*)&row_idx, (void*)&col_idx,
        (void*)&bel_x, (void*)&cms_x, (void*)&bars, (void*)&xbars,
        (void*)&xcd_cnt, (void*)&out
    };
    hipLaunchCooperativeKernel((const void*)bp_fused,
                               dim3(NBLK), dim3(NTHR), args, 0, stream);
}